// Round 1
// baseline (1161.691 us; speedup 1.0000x reference)
//
#include <hip/hip_runtime.h>

typedef __attribute__((ext_vector_type(8))) _Float16 half8;
typedef __attribute__((ext_vector_type(4))) _Float16 half4;
typedef __attribute__((ext_vector_type(4))) float f32x4;

static constexpr int NB   = 4;
static constexpr int NQ   = 65536;
static constexpr int MS   = 16384;
static constexpr int CIN  = 512;
static constexpr int COUT = 256;
static constexpr int TR   = 64;          // rows per block
static constexpr float EPSV = 1e-5f;
static constexpr float SLP  = 0.1f;

// ---------------- prep: W[K][D] fp32 -> Wt_hi/lo[D][K] f16 (transpose + 2-term split)
__global__ void prep_split(const float* __restrict__ W,
                           _Float16* __restrict__ hi, _Float16* __restrict__ lo,
                           int K, int D) {
  int i = blockIdx.x * 256 + threadIdx.x;
  if (i >= K * D) return;
  int k = i / D, d = i - k * D;          // read coalesced in d
  float v = W[i];
  _Float16 h = (_Float16)v;
  _Float16 l = (_Float16)(v - (float)h);
  hi[(size_t)d * K + k] = h;
  lo[(size_t)d * K + k] = l;
}

// LDS swizzle: row stride 512B (256 f16). XOR row into 16B-slot bits to kill
// the 16-way bank conflict on column-slice ds_read_b128 (Guideline 4).
__device__ __forceinline__ int swz(int row, int colByte) {
  return row * 512 + (colByte ^ ((row & 15) << 4));
}

__global__ void __launch_bounds__(256, 2)
fused_main(const float* __restrict__ query, const float* __restrict__ support,
           const int* __restrict__ uidx,
           const float* __restrict__ b1, const float* __restrict__ g1, const float* __restrict__ be1,
           const float* __restrict__ b2, const float* __restrict__ g2, const float* __restrict__ be2,
           const float* __restrict__ b3, const float* __restrict__ g3, const float* __restrict__ be3,
           const _Float16* __restrict__ w1h, const _Float16* __restrict__ w1l,
           const _Float16* __restrict__ w2h, const _Float16* __restrict__ w2l,
           const _Float16* __restrict__ w3h, const _Float16* __restrict__ w3l,
           float* __restrict__ out)
{
  __shared__ _Float16 sHi[TR * 256];   // 32 KiB  A-operand hi (X chunk / H)
  __shared__ _Float16 sLo[TR * 256];   // 32 KiB  A-operand lo
  __shared__ int sIdx[TR];
  char* dhi = (char*)sHi;
  char* dlo = (char*)sLo;

  const int tid  = threadIdx.x;
  const int lane = tid & 63;
  const int wid  = tid >> 6;
  const int c0   = wid * 64;           // wave's 64 output cols
  const int r0   = blockIdx.x * TR;
  const int bb   = r0 >> 16;           // batch (65536 rows per batch, no straddle)

  if (tid < TR) sIdx[tid] = uidx[r0 + tid];
  __syncthreads();

  const int arow  = lane & 15;         // A row within M-tile / B col within N-tile
  const int kslot = (lane >> 4) * 8;   // k-slot base (consistent bijection for A and B)

  f32x4 acc[4][4];

  // ================= LAYER 1 : X(64x512) @ W1 =================
  #pragma unroll
  for (int nt = 0; nt < 4; ++nt) {
    float bc = b1[c0 + nt * 16 + arow];
    #pragma unroll
    for (int mt = 0; mt < 4; ++mt) acc[mt][nt] = (f32x4){bc, bc, bc, bc};
  }

  #pragma unroll 1
  for (int ck = 0; ck < 2; ++ck) {
    // ---- gather-stage 64 rows x 256 cols of X (fp32 -> f16 hi/lo, swizzled)
    {
      int grow = tid >> 2;
      int gcol = (tid & 3) * 64;
      const float* src = support + (size_t)bb * MS * CIN
                       + (size_t)sIdx[grow] * CIN + ck * 256 + gcol;
      #pragma unroll
      for (int i = 0; i < 16; ++i) {
        f32x4 v = *(const f32x4*)(src + i * 4);
        half4 h, l;
        #pragma unroll
        for (int j = 0; j < 4; ++j) {
          _Float16 hh = (_Float16)v[j];
          h[j] = hh;
          l[j] = (_Float16)(v[j] - (float)hh);
        }
        int cb = (gcol + i * 4) * 2;
        *(half4*)(dhi + swz(grow, cb)) = h;
        *(half4*)(dlo + swz(grow, cb)) = l;
      }
    }
    __syncthreads();

    // ---- MFMA over this 256-wide K chunk
    #pragma unroll 2
    for (int ks = 0; ks < 8; ++ks) {
      int kk = ks * 32 + kslot;
      half8 Ah[4], Al[4];
      #pragma unroll
      for (int mt = 0; mt < 4; ++mt) {
        Ah[mt] = *(const half8*)(dhi + swz(mt * 16 + arow, kk * 2));
        Al[mt] = *(const half8*)(dlo + swz(mt * 16 + arow, kk * 2));
      }
      #pragma unroll
      for (int nt = 0; nt < 4; ++nt) {
        size_t wo = (size_t)(c0 + nt * 16 + arow) * 512 + ck * 256 + kk;
        half8 Bh = *(const half8*)(w1h + wo);
        half8 Bl = *(const half8*)(w1l + wo);
        #pragma unroll
        for (int mt = 0; mt < 4; ++mt) {
          acc[mt][nt] = __builtin_amdgcn_mfma_f32_16x16x32_f16(Ah[mt], Bh, acc[mt][nt], 0, 0, 0);
          acc[mt][nt] = __builtin_amdgcn_mfma_f32_16x16x32_f16(Al[mt], Bh, acc[mt][nt], 0, 0, 0);
          acc[mt][nt] = __builtin_amdgcn_mfma_f32_16x16x32_f16(Ah[mt], Bl, acc[mt][nt], 0, 0, 0);
        }
      }
    }
    __syncthreads();
  }

  // ---- GN1 + affine + leaky, write H1 (f16 hi/lo) back to LDS
  #pragma unroll
  for (int nt = 0; nt < 4; ++nt) {
    int c = c0 + nt * 16 + arow;
    float gm = g1[c], bt = be1[c];
    #pragma unroll
    for (int mt = 0; mt < 4; ++mt) {
      f32x4 v = acc[mt][nt];
      #pragma unroll
      for (int j = 0; j < 4; ++j) {
        float x = v[j];
        float s = x, q = x * x;
        s += __shfl_xor(s, 1); q += __shfl_xor(q, 1);
        s += __shfl_xor(s, 2); q += __shfl_xor(q, 2);
        s += __shfl_xor(s, 4); q += __shfl_xor(q, 4);
        float mu  = s * 0.125f;
        float var = fmaf(q, 0.125f, -mu * mu);
        float inv = rsqrtf(var + EPSV);
        float hn  = fmaf((x - mu) * inv, gm, bt);
        hn = hn >= 0.f ? hn : SLP * hn;
        int row = mt * 16 + (lane >> 4) * 4 + j;
        _Float16 hh = (_Float16)hn;
        *(_Float16*)(dhi + swz(row, c * 2)) = hh;
        *(_Float16*)(dlo + swz(row, c * 2)) = (_Float16)(hn - (float)hh);
      }
    }
  }
  __syncthreads();

  // ================= LAYER 2 : H1(64x256) @ W2 =================
  #pragma unroll
  for (int nt = 0; nt < 4; ++nt) {
    float bc = b2[c0 + nt * 16 + arow];
    #pragma unroll
    for (int mt = 0; mt < 4; ++mt) acc[mt][nt] = (f32x4){bc, bc, bc, bc};
  }
  #pragma unroll 2
  for (int ks = 0; ks < 8; ++ks) {
    int kk = ks * 32 + kslot;
    half8 Ah[4], Al[4];
    #pragma unroll
    for (int mt = 0; mt < 4; ++mt) {
      Ah[mt] = *(const half8*)(dhi + swz(mt * 16 + arow, kk * 2));
      Al[mt] = *(const half8*)(dlo + swz(mt * 16 + arow, kk * 2));
    }
    #pragma unroll
    for (int nt = 0; nt < 4; ++nt) {
      size_t wo = (size_t)(c0 + nt * 16 + arow) * 256 + kk;
      half8 Bh = *(const half8*)(w2h + wo);
      half8 Bl = *(const half8*)(w2l + wo);
      #pragma unroll
      for (int mt = 0; mt < 4; ++mt) {
        acc[mt][nt] = __builtin_amdgcn_mfma_f32_16x16x32_f16(Ah[mt], Bh, acc[mt][nt], 0, 0, 0);
        acc[mt][nt] = __builtin_amdgcn_mfma_f32_16x16x32_f16(Al[mt], Bh, acc[mt][nt], 0, 0, 0);
        acc[mt][nt] = __builtin_amdgcn_mfma_f32_16x16x32_f16(Ah[mt], Bl, acc[mt][nt], 0, 0, 0);
      }
    }
  }
  __syncthreads();   // all waves done reading H1 before X3 overwrite

  // ---- GN2 + leaky, add query, write X3 (f16 hi/lo) to LDS
  #pragma unroll
  for (int nt = 0; nt < 4; ++nt) {
    int c = c0 + nt * 16 + arow;
    float gm = g2[c], bt = be2[c];
    #pragma unroll
    for (int mt = 0; mt < 4; ++mt) {
      f32x4 v = acc[mt][nt];
      #pragma unroll
      for (int j = 0; j < 4; ++j) {
        float x = v[j];
        float s = x, q = x * x;
        s += __shfl_xor(s, 1); q += __shfl_xor(q, 1);
        s += __shfl_xor(s, 2); q += __shfl_xor(q, 2);
        s += __shfl_xor(s, 4); q += __shfl_xor(q, 4);
        float mu  = s * 0.125f;
        float var = fmaf(q, 0.125f, -mu * mu);
        float inv = rsqrtf(var + EPSV);
        float hn  = fmaf((x - mu) * inv, gm, bt);
        hn = hn >= 0.f ? hn : SLP * hn;
        int row = mt * 16 + (lane >> 4) * 4 + j;
        float x3 = hn + query[(size_t)(r0 + row) * COUT + c];
        _Float16 hh = (_Float16)x3;
        *(_Float16*)(dhi + swz(row, c * 2)) = hh;
        *(_Float16*)(dlo + swz(row, c * 2)) = (_Float16)(x3 - (float)hh);
      }
    }
  }
  __syncthreads();

  // ================= LAYER 3 : X3(64x256) @ W3 =================
  #pragma unroll
  for (int nt = 0; nt < 4; ++nt) {
    float bc = b3[c0 + nt * 16 + arow];
    #pragma unroll
    for (int mt = 0; mt < 4; ++mt) acc[mt][nt] = (f32x4){bc, bc, bc, bc};
  }
  #pragma unroll 2
  for (int ks = 0; ks < 8; ++ks) {
    int kk = ks * 32 + kslot;
    half8 Ah[4], Al[4];
    #pragma unroll
    for (int mt = 0; mt < 4; ++mt) {
      Ah[mt] = *(const half8*)(dhi + swz(mt * 16 + arow, kk * 2));
      Al[mt] = *(const half8*)(dlo + swz(mt * 16 + arow, kk * 2));
    }
    #pragma unroll
    for (int nt = 0; nt < 4; ++nt) {
      size_t wo = (size_t)(c0 + nt * 16 + arow) * 256 + kk;
      half8 Bh = *(const half8*)(w3h + wo);
      half8 Bl = *(const half8*)(w3l + wo);
      #pragma unroll
      for (int mt = 0; mt < 4; ++mt) {
        acc[mt][nt] = __builtin_amdgcn_mfma_f32_16x16x32_f16(Ah[mt], Bh, acc[mt][nt], 0, 0, 0);
        acc[mt][nt] = __builtin_amdgcn_mfma_f32_16x16x32_f16(Al[mt], Bh, acc[mt][nt], 0, 0, 0);
        acc[mt][nt] = __builtin_amdgcn_mfma_f32_16x16x32_f16(Ah[mt], Bl, acc[mt][nt], 0, 0, 0);
      }
    }
  }

  // ---- GN3 + leaky, store out
  #pragma unroll
  for (int nt = 0; nt < 4; ++nt) {
    int c = c0 + nt * 16 + arow;
    float gm = g3[c], bt = be3[c];
    #pragma unroll
    for (int mt = 0; mt < 4; ++mt) {
      f32x4 v = acc[mt][nt];
      #pragma unroll
      for (int j = 0; j < 4; ++j) {
        float x = v[j];
        float s = x, q = x * x;
        s += __shfl_xor(s, 1); q += __shfl_xor(q, 1);
        s += __shfl_xor(s, 2); q += __shfl_xor(q, 2);
        s += __shfl_xor(s, 4); q += __shfl_xor(q, 4);
        float mu  = s * 0.125f;
        float var = fmaf(q, 0.125f, -mu * mu);
        float inv = rsqrtf(var + EPSV);
        float hn  = fmaf((x - mu) * inv, gm, bt);
        hn = hn >= 0.f ? hn : SLP * hn;
        int row = mt * 16 + (lane >> 4) * 4 + j;
        out[(size_t)(r0 + row) * COUT + c] = hn;
      }
    }
  }
}

extern "C" void kernel_launch(void* const* d_in, const int* in_sizes, int n_in,
                              void* d_out, int out_size, void* d_ws, size_t ws_size,
                              hipStream_t stream) {
  const float* query   = (const float*)d_in[0];
  const float* support = (const float*)d_in[1];
  const int*   uidx    = (const int*)d_in[2];
  const float* W1  = (const float*)d_in[3];
  const float* b1  = (const float*)d_in[4];
  const float* g1  = (const float*)d_in[5];
  const float* be1 = (const float*)d_in[6];
  const float* W2  = (const float*)d_in[7];
  const float* b2  = (const float*)d_in[8];
  const float* g2  = (const float*)d_in[9];
  const float* be2 = (const float*)d_in[10];
  const float* W3  = (const float*)d_in[11];
  const float* b3  = (const float*)d_in[12];
  const float* g3  = (const float*)d_in[13];
  const float* be3 = (const float*)d_in[14];
  float* out = (float*)d_out;

  char* ws = (char*)d_ws;
  _Float16* w1h = (_Float16*)ws;                  // [256][512]
  _Float16* w1l = w1h + (size_t)CIN * COUT;
  _Float16* w2h = w1l + (size_t)CIN * COUT;       // [256][256]
  _Float16* w2l = w2h + (size_t)COUT * COUT;
  _Float16* w3h = w2l + (size_t)COUT * COUT;
  _Float16* w3l = w3h + (size_t)COUT * COUT;

  prep_split<<<(CIN * COUT + 255) / 256, 256, 0, stream>>>(W1, w1h, w1l, CIN, COUT);
  prep_split<<<(COUT * COUT + 255) / 256, 256, 0, stream>>>(W2, w2h, w2l, COUT, COUT);
  prep_split<<<(COUT * COUT + 255) / 256, 256, 0, stream>>>(W3, w3h, w3l, COUT, COUT);

  fused_main<<<(NB * NQ) / TR, 256, 0, stream>>>(
      query, support, uidx,
      b1, g1, be1, b2, g2, be2, b3, g3, be3,
      w1h, w1l, w2h, w2l, w3h, w3l, out);
}